// Round 2
// baseline (271.778 us; speedup 1.0000x reference)
//
#include <hip/hip_runtime.h>

// LengthRegulator: expand x[B,L,D] along L per integer durations into out[B,T,D].
// B=64, L=256, D=512, T=max_length=1792 (fixed by setup_inputs).
// Output tuple: (out [B,T,D] f32, max_length scalar) -> d_out flat, f32.
//
// v2b: phoneme->frame SCATTER into an LDS idx tile (replaces per-frame binary
// search: 64 dependent LDS round-trips/thread, latency-bound ~1.1 TB/s).
// Copy loop: 1 LDS read + 1 independent global load + 1 nontemporal store
// per iter -> store-BW-bound. TILE=64 amortizes the per-block scan 4x.
// Fix vs v2: use native ext_vector_type for nontemporal store (HIP float4
// is a class type, rejected by the builtin).

#define BB 64
#define LL 256
#define DD 512
#define TT 1792
#define D4 (DD / 4)      // 128 float4 per row
#define TILE 64          // frames per block; TT = 28 * TILE exact
#define NBT (TT / TILE)  // 28

typedef float f32x4 __attribute__((ext_vector_type(4)));

__global__ __launch_bounds__(256) void length_regulator_kernel(
    const f32x4* __restrict__ x4,       // [B, L, D4]
    const int*   __restrict__ dur,      // [B, L]
    const int*   __restrict__ maxlen,   // [1]
    float*       __restrict__ out)      // [B*T*D + 1]
{
    __shared__ int cum[LL];
    __shared__ int idx_s[TILE];
    const int tid = threadIdx.x;
    const int b   = blockIdx.y;
    const int t0  = blockIdx.x * TILE;

    // --- inclusive scan of durations for row b (Hillis-Steele, 8 steps) ---
    // ALPHA = 1.0 -> round(d * 1.0) == d
    cum[tid] = dur[b * LL + tid];
    if (tid < TILE) idx_s[tid] = -1;  // -1 = "zero frame" (t >= total)
    __syncthreads();
    #pragma unroll
    for (int off = 1; off < LL; off <<= 1) {
        int v = (tid >= off) ? cum[tid - off] : 0;
        __syncthreads();
        cum[tid] += v;
        __syncthreads();
    }
    int total = cum[LL - 1];
    // all-zero row: d[0] = 1 -> cum[j] = 1 for all j
    if (total == 0) cum[tid] = 1;
    __syncthreads();

    // --- scatter: thread j stamps its phoneme index over [cum[j-1], cum[j]) ---
    // Exactly reproduces searchsorted(cum, t, side='right'): the unique j with
    // d[j] > 0 and cum[j-1] <= t < cum[j]. O(duration) <= 7 LDS writes/thread.
    {
        const int end   = cum[tid];
        const int start = (tid > 0) ? cum[tid - 1] : 0;
        const int lo = max(start, t0);
        const int hi = min(end, t0 + TILE);
        for (int t = lo; t < hi; ++t) idx_s[t - t0] = tid;
    }
    __syncthreads();

    // --- copy: 2 groups x 128 lanes; each group copies one D-row per iter ---
    // All iterations independent: no dependent chains, compiler can keep
    // many loads in flight.
    f32x4* out4 = (f32x4*)out;
    const int group = tid >> 7;   // 0..1
    const int lane  = tid & 127;  // float4 index within row
    const f32x4 z   = (f32x4)(0.f);

    #pragma unroll
    for (int it = 0; it < TILE / 2; ++it) {
        const int toff = it * 2 + group;       // frame offset within tile
        const int id   = idx_s[toff];          // wave-uniform (t uniform per wave)
        f32x4 v = z;
        if (id >= 0)                           // wave-uniform branch, no divergence
            v = x4[((size_t)b * LL + id) * D4 + lane];
        // write-once stream: bypass cache so x rows stay L2-resident
        __builtin_nontemporal_store(v, &out4[((size_t)b * TT + t0 + toff) * D4 + lane]);
    }

    // --- output 1: max_length as float, one thread writes it ---
    if (b == 0 && blockIdx.x == 0 && tid == 0) {
        out[(size_t)BB * TT * DD] = (float)maxlen[0];
    }
}

extern "C" void kernel_launch(void* const* d_in, const int* in_sizes, int n_in,
                              void* d_out, int out_size, void* d_ws, size_t ws_size,
                              hipStream_t stream) {
    const f32x4* x4  = (const f32x4*)d_in[0];
    const int*   dur = (const int*)d_in[1];
    const int*   ml  = (const int*)d_in[2];
    float*       out = (float*)d_out;

    dim3 grid(NBT, BB);  // (28, 64) blocks, 256 threads each
    length_regulator_kernel<<<grid, dim3(256), 0, stream>>>(x4, dur, ml, out);
}

// Round 4
// 269.788 us; speedup vs baseline: 1.0074x; 1.0074x over previous
//
#include <hip/hip_runtime.h>

// LengthRegulator: expand x[B,L,D] along L per integer durations into out[B,T,D].
// B=64, L=256, D=512, T=max_length=1792 (fixed by setup_inputs).
// Output tuple: (out [B,T,D] f32, max_length scalar) -> d_out flat, f32.
//
// v3: the measured dur_us includes a ~149us harness poison-fill; the kernel
// itself is ~122us (absent from rocprof top-5, cutoff 146us) at ~2 TB/s
// effective vs 6.3 TB/s proven by the fill on the same buffer. Attack the
// gather+stream wall:
//  - branchless copy loop (clamped unconditional load + select) so the
//    compiler can batch loads instead of per-iteration exec-mask chains
//  - XCD-locality swizzle: XCD k gets b in [8k, 8k+8) -> x working set
//    8*512KB = 4MB = one L2; gathers become L2 hits instead of L3 misses
//  - NT stores keep the 235MB output stream from evicting x out of L2

#define BB 64
#define LL 256
#define DD 512
#define TT 1792
#define D4 (DD / 4)          // 128 float4 per row
#define TILE 64              // frames per block; TT = 28 * TILE exact
#define NBT (TT / TILE)      // 28 t-blocks per b
#define NBLK (BB * NBT)      // 1792 blocks

typedef float f32x4 __attribute__((ext_vector_type(4)));

__global__ __launch_bounds__(256) void length_regulator_kernel(
    const f32x4* __restrict__ x4,       // [B, L, D4]
    const int*   __restrict__ dur,      // [B, L]
    const int*   __restrict__ maxlen,   // [1]
    float*       __restrict__ out)      // [B*T*D + 1]
{
    __shared__ int cum[LL];
    __shared__ int idx_s[TILE];
    const int tid = threadIdx.x;

    // XCD-locality swizzle (perf heuristic: XCD = blockIdx.x % 8).
    // virt enumerates (b, t-block) so that each XCD owns 8 consecutive b's.
    const int bid  = blockIdx.x;
    const int virt = (bid & 7) * (NBLK / 8) + (bid >> 3);
    const int b    = virt / NBT;
    const int t0   = (virt % NBT) * TILE;

    // --- inclusive scan of durations for row b (Hillis-Steele, 8 steps) ---
    // ALPHA = 1.0 -> round(d * 1.0) == d
    cum[tid] = dur[b * LL + tid];
    if (tid < TILE) idx_s[tid] = -1;  // -1 = "zero frame" (t >= total)
    __syncthreads();
    #pragma unroll
    for (int off = 1; off < LL; off <<= 1) {
        int v = (tid >= off) ? cum[tid - off] : 0;
        __syncthreads();
        cum[tid] += v;
        __syncthreads();
    }
    // all-zero row: d[0] = 1 -> cum[j] = 1 for all j
    if (cum[LL - 1] == 0) cum[tid] = 1;
    __syncthreads();

    // --- scatter: thread j stamps its phoneme index over [cum[j-1], cum[j]) ---
    // Reproduces searchsorted(cum, t, 'right'): unique j with d[j] > 0 and
    // cum[j-1] <= t < cum[j]. O(duration) <= 7 LDS writes/thread.
    {
        const int end   = cum[tid];
        const int start = (tid > 0) ? cum[tid - 1] : 0;
        const int lo = max(start, t0);
        const int hi = min(end, t0 + TILE);
        for (int t = lo; t < hi; ++t) idx_s[t - t0] = tid;
    }
    __syncthreads();

    // --- copy: 2 groups x 128 lanes; one D-row per group per iter ---
    // Branchless: clamped unconditional load + vector select. All 32
    // iterations independent straight-line -> compiler batches loads.
    const int group = tid >> 7;   // 0..1
    const int lane  = tid & 127;  // float4 index within row
    const f32x4 z   = (f32x4)(0.f);
    const f32x4* __restrict__ xrow = x4 + (size_t)b * LL * D4;
    f32x4* __restrict__ outb = (f32x4*)out + ((size_t)b * TT + t0) * D4;

    #pragma unroll
    for (int it = 0; it < TILE / 2; ++it) {
        const int toff = it * 2 + group;     // frame offset within tile
        const int id   = idx_s[toff];        // uniform per wave
        const int idc  = (id >= 0) ? id : 0; // clamp: always load a valid row
        f32x4 v = xrow[idc * D4 + lane];
        v = (id >= 0) ? v : z;               // select, no branch
        // write-once stream: keep output from evicting x in L2
        __builtin_nontemporal_store(v, outb + toff * D4 + lane);
    }

    // --- output 1: max_length as float, one thread writes it ---
    if (virt == 0 && tid == 0) {
        out[(size_t)BB * TT * DD] = (float)maxlen[0];
    }
}

extern "C" void kernel_launch(void* const* d_in, const int* in_sizes, int n_in,
                              void* d_out, int out_size, void* d_ws, size_t ws_size,
                              hipStream_t stream) {
    const f32x4* x4  = (const f32x4*)d_in[0];
    const int*   dur = (const int*)d_in[1];
    const int*   ml  = (const int*)d_in[2];
    float*       out = (float*)d_out;

    length_regulator_kernel<<<dim3(NBLK), dim3(256), 0, stream>>>(x4, dur, ml, out);
}